// Round 5
// baseline (2250.845 us; speedup 1.0000x reference)
//
#include <hip/hip_runtime.h>
#include <math.h>

#define NOUTK 1024
#define PHK   512
#define HID   24
#define G4    96
#define LSTEPS 32
#define BATCH 8192
#define EPB   8

// Static LDS: 62,304 B. Chosen so LDS admits EXACTLY 2 blocks/CU (124.6 KB of
// 160 KB; 3 blocks would need 187 KB): with 512-thread blocks that is 16
// waves/CU = 4 waves/EU -- the allocator's occupancy target -- giving a
// 128-VGPR budget. R3/R4's 1024-thread/64KB-LDS geometry made the target 8
// waves/EU -> 64 VGPRs -> the f64 working set spilled: 4.7 GB/launch of
// scratch traffic at 2.1 TB/s WAS the 2245 us runtime.
struct Smem {
  float  stg[HID][64][8];    // active w_lin half f32 [k][chunk][col]   49152 B
  float  whhT[HID][G4];      // w_hh transposed [k][row]                 9216 B
  float  bihs[G4], bhhs[G4]; //                                           768 B
  double hsh[EPB][25];       // h state f64 (pad 25 -> conflict-free)    1600 B
  double scr[8][EPB];        // max/sum partials + candr alias            512 B
  double tots[8][EPB];       // per-slice prob totals                     512 B
  double Msh[EPB], invSm[EPB], ush[EPB], r0sh[EPB];                  //   256 B
  int    candj[8][EPB];      //                                           256 B
  int    actsh[EPB];         // previous action (-1 = zeros one-hot)       32 B
};

__device__ __forceinline__ float bf2f(unsigned short v) {
  union { unsigned u; float f; } x; x.u = ((unsigned)v) << 16; return x.f;
}
__device__ __forceinline__ unsigned short f2bf(float f) {
  unsigned u = __float_as_uint(f);
  unsigned r = 0x7FFFu + ((u >> 16) & 1u);
  return (unsigned short)((u + r) >> 16);
}
__device__ __forceinline__ float bfsnap(float f) { return bf2f(f2bf(f)); }

__attribute__((amdgpu_flat_work_group_size(512, 512), amdgpu_waves_per_eu(4, 4)))
__global__ void
policy_kernel(const float* __restrict__ wihf,  const float* __restrict__ whhf,
              const float* __restrict__ bihf,  const float* __restrict__ bhhf,
              const float* __restrict__ wlinf, const float* __restrict__ blinf,
              const float* __restrict__ uf,    float* __restrict__ outg) {
  __shared__ Smem sm;
  const int tid  = threadIdx.x;
  const int wave = tid >> 6;                // 8 waves; wave w owns element w
  const int lane = tid & 63;
  const int s    = wave;                    // slice: 64 active cols
  const int le   = lane & 7;                // element within group
  const int jl   = lane >> 3;               // 8-col chunk within slice
  const int eG   = le;                      // element this thread computes for
  const int geL  = blockIdx.x * EPB + wave; // owner's global batch element
  const int jgl0 = s * 64 + jl * 8;         // active-local col of r=0
  const int c    = s * 8 + jl;              // stg chunk

  // ---------------- one-time staging ----------------
  for (int i = tid; i < G4 * HID; i += 512) {
    const int row = i / HID, k = i % HID;   // coalesced global read
    sm.whhT[k][row] = whhf[i];
  }
  if (tid < G4) { sm.bihs[tid] = bihf[tid]; sm.bhhs[tid] = bhhf[tid]; }
  if (tid < EPB * 25) ((double*)sm.hsh)[tid] = 0.0;
  if (tid < EPB) sm.actsh[tid] = -1;

  const float4* bl4 = (const float4*)blinf;
  // Thread t owns w_lin row t of the active half: 6 float4s (L2/L3-resident
  // after step 0; 96 KB total). Stash becomes stride-1 LDS writes
  // (bank = tid%32, 2-way across 64 lanes = free) -- kills the 3.5e7
  // SQ_LDS_BANK_CONFLICT of the R4 scatter-stash.
  float4 pf[6];
  {
    const float4* nrow = (const float4*)(wlinf + tid * HID);   // t=0: even half
    #pragma unroll
    for (int q = 0; q < 6; ++q) pf[q] = nrow[q];
  }

  double creg = 0.0;                        // c state: lanes<24 of owner wave
  __syncthreads();

  for (int t = 0; t < LSTEPS; ++t) {
    const int odd  = t & 1;
    const int base = odd ? PHK : 0;

    // ---- stash prefetched row to LDS, then prefetch step t+1's row ----
    #pragma unroll
    for (int q = 0; q < 6; ++q) {
      const float4 v = pf[q];
      sm.stg[q * 4 + 0][tid >> 3][tid & 7] = v.x;
      sm.stg[q * 4 + 1][tid >> 3][tid & 7] = v.y;
      sm.stg[q * 4 + 2][tid >> 3][tid & 7] = v.z;
      sm.stg[q * 4 + 3][tid >> 3][tid & 7] = v.w;
    }
    {
      const float4* nrow = (const float4*)(wlinf + (((t + 1) & 1) * PHK + tid) * HID);
      #pragma unroll
      for (int q = 0; q < 6; ++q) pf[q] = nrow[q];
    }
    // bias for this step (consumed after the GEMM, ~3000 cy later)
    const float4 bza = bl4[(base + jgl0) >> 2];
    const float4 bzb = bl4[((base + jgl0) >> 2) + 1];
    if (lane == 32) sm.ush[wave] = (double)uf[t * BATCH + geL];

    // ---------------- phase L: LSTM cell (owner wave, lanes 0..23) -------
    if (lane < HID) {
      const int a = sm.actsh[wave];
      double hk[HID];
      #pragma unroll
      for (int k = 0; k < HID; ++k) hk[k] = sm.hsh[wave][k];
      double g[4];
      #pragma unroll
      for (int q = 0; q < 4; ++q) {
        const int row = q * HID + lane;
        const double colA = (a >= 0) ? (double)wihf[row * NOUTK + a] : 0.0;
        double mv = 0.0;
        #pragma unroll
        for (int k = 0; k < HID; ++k)
          mv = fma(hk[k], (double)sm.whhT[k][row], mv);
        g[q] = ((colA + (double)sm.bihs[row]) + mv) + (double)sm.bhhs[row];
      }
      const double ig = 1.0 / (1.0 + exp(-g[0]));
      const double fg = 1.0 / (1.0 + exp(-g[1]));
      const double gv = tanh(g[2]);
      const double og = 1.0 / (1.0 + exp(-g[3]));
      creg = fg * creg + ig * gv;
      sm.hsh[wave][lane] = og * tanh(creg);
    }
    __syncthreads();                                  // b1

    // ---------------- phase G: active-half logits (8 cols/thread, f64) ---
    double z[8];
    #pragma unroll
    for (int r = 0; r < 8; ++r) z[r] = 0.0;
    #pragma unroll
    for (int k = 0; k < HID; ++k) {
      const double hk = sm.hsh[eG][k];
      const float4 wa = *(const float4*)&sm.stg[k][c][0];
      const float4 wb = *(const float4*)&sm.stg[k][c][4];
      z[0] = fma(hk, (double)wa.x, z[0]); z[1] = fma(hk, (double)wa.y, z[1]);
      z[2] = fma(hk, (double)wa.z, z[2]); z[3] = fma(hk, (double)wa.w, z[3]);
      z[4] = fma(hk, (double)wb.x, z[4]); z[5] = fma(hk, (double)wb.y, z[5]);
      z[6] = fma(hk, (double)wb.z, z[6]); z[7] = fma(hk, (double)wb.w, z[7]);
    }
    z[0] += (double)bza.x; z[1] += (double)bza.y; z[2] += (double)bza.z; z[3] += (double)bza.w;
    z[4] += (double)bzb.x; z[5] += (double)bzb.y; z[6] += (double)bzb.z; z[7] += (double)bzb.w;

    // ---------------- softmax max over active half ----
    // (e_i/Sm is invariant to max shift and the full-softmax denominator to
    //  ~1e-16 relative — safe at f64 decision margins)
    double pm = z[0];
    #pragma unroll
    for (int r = 1; r < 8; ++r) pm = fmax(pm, z[r]);
    pm = fmax(pm, __shfl_xor(pm, 8));
    pm = fmax(pm, __shfl_xor(pm, 16));
    pm = fmax(pm, __shfl_xor(pm, 32));
    if (jl == 0) sm.scr[s][eG] = pm;
    __syncthreads();                                  // b2
    if (lane < 8) {
      double v = sm.scr[lane][wave];
      v = fmax(v, __shfl_xor(v, 1));
      v = fmax(v, __shfl_xor(v, 2));
      v = fmax(v, __shfl_xor(v, 4));
      if (lane == 0) sm.Msh[wave] = v;
    }
    __syncthreads();                                  // b3

    // ---------------- exp (in place) + masked-sum Sm -> inv ----
    const double Me = sm.Msh[eG];
    double ps = 0.0;
    #pragma unroll
    for (int r = 0; r < 8; ++r) { z[r] = exp(z[r] - Me); ps += z[r]; }
    ps += __shfl_xor(ps, 8);
    ps += __shfl_xor(ps, 16);
    ps += __shfl_xor(ps, 32);
    if (jl == 0) sm.scr[s][eG] = ps;
    __syncthreads();                                  // b4
    if (lane < 8) {
      double v = sm.scr[lane][wave];
      v += __shfl_xor(v, 1);
      v += __shfl_xor(v, 2);
      v += __shfl_xor(v, 4);
      if (lane == 0) sm.invSm[wave] = 1.0 / v;
    }
    __syncthreads();                                  // b5

    // ---------------- rr = e/Sm (in place), blocked prefix ----
    const double inv = sm.invSm[eG];
    double pref[8];
    #pragma unroll
    for (int r = 0; r < 8; ++r) z[r] = z[r] * inv;
    pref[0] = z[0];
    #pragma unroll
    for (int r = 1; r < 8; ++r) pref[r] = pref[r - 1] + z[r];
    const double tch = pref[7];
    double exbase = 0.0, acc = 0.0;
    #pragma unroll
    for (int q2 = 0; q2 < 8; ++q2) {
      const double tq = __shfl(tch, q2 * 8 + le);
      if (q2 == jl) exbase = acc;
      acc += tq;
    }
    if (jl == 0) sm.tots[s][eG] = acc;
    if (s == 0 && lane < 8) sm.r0sh[eG] = z[0];
    __syncthreads();                                  // b6

    // ---------------- crossing search ----
    double sb = exbase;
    for (int i = 0; i < s; ++i) sb += sm.tots[i][eG];
    const double ue = sm.ush[eG];
    int jloc = 0x7FFFFFFF; double rsel = 0.0;
    #pragma unroll
    for (int r = 0; r < 8; ++r) {
      const double C = sb + pref[r];
      if (jloc == 0x7FFFFFFF && C > ue) { jloc = jgl0 + r; rsel = z[r]; }
    }
    { int oj = __shfl_xor(jloc, 8);  double orr = __shfl_xor(rsel, 8);  if (oj < jloc) { jloc = oj; rsel = orr; } }
    { int oj = __shfl_xor(jloc, 16); double orr = __shfl_xor(rsel, 16); if (oj < jloc) { jloc = oj; rsel = orr; } }
    { int oj = __shfl_xor(jloc, 32); double orr = __shfl_xor(rsel, 32); if (oj < jloc) { jloc = oj; rsel = orr; } }
    if (jl == 0) { sm.candj[s][eG] = jloc; sm.scr[s][eG] = rsel; }
    __syncthreads();                                  // b7

    // ---------------- owner: combine slices, emit ----
    // (no trailing barrier: b1(t+1) already fences every LDS reuse)
    if (lane < 8) {
      int cj = sm.candj[lane][wave]; double cr = sm.scr[lane][wave];
      { int oj = __shfl_xor(cj, 1); double orr = __shfl_xor(cr, 1); if (oj < cj) { cj = oj; cr = orr; } }
      { int oj = __shfl_xor(cj, 2); double orr = __shfl_xor(cr, 2); if (oj < cj) { cj = oj; cr = orr; } }
      { int oj = __shfl_xor(cj, 4); double orr = __shfl_xor(cr, 4); if (oj < cj) { cj = oj; cr = orr; } }
      if (lane == 0) {
        int actg; double p;
        if (cj == 0x7FFFFFFF) {               // cumsum never exceeded u:
          actg = 0;                           // np.argmax(all False) == 0
          p = odd ? 0.0 : sm.r0sh[wave];      // out[0] (masked -> 0 on odd)
        } else {
          actg = base + cj; p = cr;
        }
        sm.actsh[wave] = actg;
        const int io = geL * LSTEPS + t;
        outg[io]                  = bfsnap((float)p);
        outg[BATCH * LSTEPS + io] = bfsnap((float)actg);
      }
    }
  }
}

extern "C" void kernel_launch(void* const* d_in, const int* in_sizes, int n_in,
                              void* d_out, int out_size, void* d_ws, size_t ws_size,
                              hipStream_t stream) {
  (void)in_sizes; (void)n_in; (void)out_size; (void)d_ws; (void)ws_size;
  policy_kernel<<<BATCH / EPB, 512, 0, stream>>>(
      (const float*)d_in[0], (const float*)d_in[1], (const float*)d_in[2],
      (const float*)d_in[3], (const float*)d_in[4], (const float*)d_in[5],
      (const float*)d_in[6], (float*)d_out);
}

// Round 6
// 1919.103 us; speedup vs baseline: 1.1729x; 1.1729x over previous
//
#include <hip/hip_runtime.h>
#include <math.h>

#define NOUTK 1024
#define PHK   512
#define HID   24
#define G4    96
#define LSTEPS 32
#define BATCH 8192
#define EPB   16

// Dynamic LDS: 118,720 B (opt-in via hipFuncSetAttribute; executes fine --
// proven in R2 which ran with 144 KB). One block/CU (LDS-forced), 16 waves.
// Both w_lin halves resident => no per-step staging at all.
struct SmemD {
  float  stg[HID][128][8];   // w_lin, BOTH halves [k][chunk][col]      98304 B
  float  whhT[HID][G4];      // w_hh transposed [k][row]                 9216 B
  float  blin[NOUTK];        // b_lin f32                                4096 B
  float  bihs[G4], bhhs[G4]; //                                           768 B
  double hsh[EPB][25];       // h state f64 (pad 25 -> conflict-free)    3200 B
  double scr[8][EPB];        // max/sum partials + candr alias           1024 B
  double tots[8][EPB];       // per-slice prob totals                    1024 B
  double Msh[EPB], invSm[EPB], ush[EPB], r0sh[EPB];                  //   512 B
  int    candj[8][EPB];      //                                           512 B
  int    actsh[EPB];         // previous action (-1 = zeros one-hot)       64 B
};

__device__ __forceinline__ float bf2f(unsigned short v) {
  union { unsigned u; float f; } x; x.u = ((unsigned)v) << 16; return x.f;
}
__device__ __forceinline__ unsigned short f2bf(float f) {
  unsigned u = __float_as_uint(f);
  unsigned r = 0x7FFFu + ((u >> 16) & 1u);
  return (unsigned short)((u + r) >> 16);
}
__device__ __forceinline__ float bfsnap(float f) { return bf2f(f2bf(f)); }

// R3/R4/R5 all allocated 64 VGPRs regardless of occupancy attributes, leaving
// the f64 arrays (z[8]/pref[8]/hk[24]) RESIDENT IN SCRATCH: 3.6 GB/launch of
// HBM write traffic == the whole runtime. This version has ZERO local arrays
// (named scalars only) and a peak live set of ~50 VGPRs, so even a 64-VGPR
// allocation spills nothing.
__global__ void __launch_bounds__(1024)
policy_kernel(const float* __restrict__ wihf,  const float* __restrict__ whhf,
              const float* __restrict__ bihf,  const float* __restrict__ bhhf,
              const float* __restrict__ wlinf, const float* __restrict__ blinf,
              const float* __restrict__ uf,    float* __restrict__ outg) {
  extern __shared__ char smraw[];
  SmemD* sm = (SmemD*)smraw;
  const int tid  = threadIdx.x;
  const int wave = tid >> 6;                // 16 waves; wave w owns element w
  const int lane = tid & 63;
  const int s    = wave & 7;                // slice: 64 active cols
  const int eg   = (wave >> 3) << 3;        // element group base (0 or 8)
  const int le   = lane & 7;                // element within group
  const int jl   = lane >> 3;               // 8-col chunk within slice
  const int eG   = eg + le;                 // element this thread computes for
  const int geL  = blockIdx.x * EPB + wave; // owner's global batch element
  const int jgl0 = s * 64 + jl * 8;         // active-local col of r=0

  // ---------------- one-time staging (both w_lin halves!) ----------------
  {
    const float4* row4 = (const float4*)(wlinf + tid * HID);  // row j = tid
    #pragma unroll
    for (int q = 0; q < 6; ++q) {
      const float4 v = row4[q];
      sm->stg[q * 4 + 0][tid >> 3][tid & 7] = v.x;
      sm->stg[q * 4 + 1][tid >> 3][tid & 7] = v.y;
      sm->stg[q * 4 + 2][tid >> 3][tid & 7] = v.z;
      sm->stg[q * 4 + 3][tid >> 3][tid & 7] = v.w;
    }
  }
  for (int i = tid; i < G4 * HID; i += 1024) {
    const int row = i / HID, k = i % HID;   // coalesced global read
    sm->whhT[k][row] = whhf[i];
  }
  sm->blin[tid] = blinf[tid];
  if (tid < G4) { sm->bihs[tid] = bihf[tid]; sm->bhhs[tid] = bhhf[tid]; }
  if (tid < EPB * 25) ((double*)sm->hsh)[tid] = 0.0;
  if (tid < EPB) sm->actsh[tid] = -1;

  double creg = 0.0;                        // c state: lanes<24 of owner wave
  __syncthreads();

  for (int t = 0; t < LSTEPS; ++t) {
    const int odd  = t & 1;
    const int base = odd ? PHK : 0;
    const int c    = (base >> 3) + s * 8 + jl;   // stg chunk for this parity

    if (lane == 32) sm->ush[wave] = (double)uf[t * BATCH + geL];

    // ---------------- phase L: LSTM cell (owner wave, lanes 0..23) -------
    // h re-read from LDS per fma (broadcast, conflict-free) instead of a
    // 48-VGPR hk[24] array. Op order identical to the passing R4 kernel.
    if (lane < HID) {
      const int a = sm->actsh[wave];
      double g0, g1, g2, g3;
#define GATE(Q, GOUT)                                                        \
      { const int row = (Q) * HID + lane;                                    \
        const double colA = (a >= 0) ? (double)wihf[row * NOUTK + a] : 0.0;  \
        double mv = 0.0;                                                     \
        _Pragma("unroll")                                                    \
        for (int k = 0; k < HID; ++k)                                        \
          mv = fma(sm->hsh[wave][k], (double)sm->whhT[k][row], mv);          \
        GOUT = ((colA + (double)sm->bihs[row]) + mv) + (double)sm->bhhs[row]; }
      GATE(0, g0) GATE(1, g1) GATE(2, g2) GATE(3, g3)
#undef GATE
      const double ig = 1.0 / (1.0 + exp(-g0));
      const double fg = 1.0 / (1.0 + exp(-g1));
      const double gv = tanh(g2);
      const double og = 1.0 / (1.0 + exp(-g3));
      creg = fg * creg + ig * gv;
      sm->hsh[wave][lane] = og * tanh(creg);
    }
    __syncthreads();                                  // b1

    // ---------------- phase G: active-half logits (8 cols/thread, f64) ---
    double z0 = 0.0, z1 = 0.0, z2 = 0.0, z3 = 0.0,
           z4 = 0.0, z5 = 0.0, z6 = 0.0, z7 = 0.0;
    for (int k = 0; k < HID; ++k) {
      const double hv = sm->hsh[eG][k];
      const float4 wa = *(const float4*)&sm->stg[k][c][0];
      const float4 wb = *(const float4*)&sm->stg[k][c][4];
      z0 = fma(hv, (double)wa.x, z0); z1 = fma(hv, (double)wa.y, z1);
      z2 = fma(hv, (double)wa.z, z2); z3 = fma(hv, (double)wa.w, z3);
      z4 = fma(hv, (double)wb.x, z4); z5 = fma(hv, (double)wb.y, z5);
      z6 = fma(hv, (double)wb.z, z6); z7 = fma(hv, (double)wb.w, z7);
    }
    {
      const float4 ba = *(const float4*)&sm->blin[base + jgl0];
      const float4 bb = *(const float4*)&sm->blin[base + jgl0 + 4];
      z0 += (double)ba.x; z1 += (double)ba.y; z2 += (double)ba.z; z3 += (double)ba.w;
      z4 += (double)bb.x; z5 += (double)bb.y; z6 += (double)bb.z; z7 += (double)bb.w;
    }

    // ---------------- softmax max over active half ----
    // (e_i/Sm is invariant to max shift and the full-softmax denominator to
    //  ~1e-16 relative — safe at f64 decision margins)
    double pm = fmax(fmax(fmax(z0, z1), fmax(z2, z3)),
                     fmax(fmax(z4, z5), fmax(z6, z7)));
    pm = fmax(pm, __shfl_xor(pm, 8));
    pm = fmax(pm, __shfl_xor(pm, 16));
    pm = fmax(pm, __shfl_xor(pm, 32));
    if (jl == 0) sm->scr[s][eG] = pm;
    __syncthreads();                                  // b2
    if (lane < 8) {
      double v = sm->scr[lane][wave];
      v = fmax(v, __shfl_xor(v, 1));
      v = fmax(v, __shfl_xor(v, 2));
      v = fmax(v, __shfl_xor(v, 4));
      if (lane == 0) sm->Msh[wave] = v;
    }
    __syncthreads();                                  // b3

    // ---------------- exp (in place) + masked-sum Sm -> inv ----
    const double Me = sm->Msh[eG];
    z0 = exp(z0 - Me); z1 = exp(z1 - Me); z2 = exp(z2 - Me); z3 = exp(z3 - Me);
    z4 = exp(z4 - Me); z5 = exp(z5 - Me); z6 = exp(z6 - Me); z7 = exp(z7 - Me);
    double ps = ((((((z0 + z1) + z2) + z3) + z4) + z5) + z6) + z7;
    ps += __shfl_xor(ps, 8);
    ps += __shfl_xor(ps, 16);
    ps += __shfl_xor(ps, 32);
    if (jl == 0) sm->scr[s][eG] = ps;
    __syncthreads();                                  // b4
    if (lane < 8) {
      double v = sm->scr[lane][wave];
      v += __shfl_xor(v, 1);
      v += __shfl_xor(v, 2);
      v += __shfl_xor(v, 4);
      if (lane == 0) sm->invSm[wave] = 1.0 / v;
    }
    __syncthreads();                                  // b5

    // ---------------- rr = e/Sm (in place), blocked prefix ----
    const double inv = sm->invSm[eG];
    z0 *= inv; z1 *= inv; z2 *= inv; z3 *= inv;
    z4 *= inv; z5 *= inv; z6 *= inv; z7 *= inv;
    const double p0 = z0,      p1 = p0 + z1, p2 = p1 + z2, p3 = p2 + z3,
                 p4 = p3 + z4, p5 = p4 + z5, p6 = p5 + z6, p7 = p6 + z7;
    double exbase = 0.0, acc = 0.0;
    #pragma unroll
    for (int q2 = 0; q2 < 8; ++q2) {
      const double tq = __shfl(p7, q2 * 8 + le);
      if (q2 == jl) exbase = acc;
      acc += tq;
    }
    if (jl == 0) sm->tots[s][eG] = acc;
    if (s == 0 && lane < 8) sm->r0sh[eG] = z0;
    __syncthreads();                                  // b6

    // ---------------- crossing search ----
    double sb = exbase;
    for (int i = 0; i < s; ++i) sb += sm->tots[i][eG];
    const double ue = sm->ush[eG];
    int jloc = 0x7FFFFFFF; double rsel = 0.0;
#define CROSS(R, PR, ZR)                                                     \
    { const double C = sb + PR;                                              \
      if (jloc == 0x7FFFFFFF && C > ue) { jloc = jgl0 + (R); rsel = ZR; } }
    CROSS(0, p0, z0) CROSS(1, p1, z1) CROSS(2, p2, z2) CROSS(3, p3, z3)
    CROSS(4, p4, z4) CROSS(5, p5, z5) CROSS(6, p6, z6) CROSS(7, p7, z7)
#undef CROSS
    { int oj = __shfl_xor(jloc, 8);  double orr = __shfl_xor(rsel, 8);  if (oj < jloc) { jloc = oj; rsel = orr; } }
    { int oj = __shfl_xor(jloc, 16); double orr = __shfl_xor(rsel, 16); if (oj < jloc) { jloc = oj; rsel = orr; } }
    { int oj = __shfl_xor(jloc, 32); double orr = __shfl_xor(rsel, 32); if (oj < jloc) { jloc = oj; rsel = orr; } }
    if (jl == 0) { sm->candj[s][eG] = jloc; sm->scr[s][eG] = rsel; }
    __syncthreads();                                  // b7

    // ---------------- owner: combine slices, emit ----
    // (no trailing barrier: b1(t+1) already fences every LDS reuse)
    if (lane < 8) {
      int cj = sm->candj[lane][wave]; double cr = sm->scr[lane][wave];
      { int oj = __shfl_xor(cj, 1); double orr = __shfl_xor(cr, 1); if (oj < cj) { cj = oj; cr = orr; } }
      { int oj = __shfl_xor(cj, 2); double orr = __shfl_xor(cr, 2); if (oj < cj) { cj = oj; cr = orr; } }
      { int oj = __shfl_xor(cj, 4); double orr = __shfl_xor(cr, 4); if (oj < cj) { cj = oj; cr = orr; } }
      if (lane == 0) {
        int actg; double p;
        if (cj == 0x7FFFFFFF) {               // cumsum never exceeded u:
          actg = 0;                           // np.argmax(all False) == 0
          p = odd ? 0.0 : sm->r0sh[wave];     // out[0] (masked -> 0 on odd)
        } else {
          actg = base + cj; p = cr;
        }
        sm->actsh[wave] = actg;
        const int io = geL * LSTEPS + t;
        outg[io]                  = bfsnap((float)p);
        outg[BATCH * LSTEPS + io] = bfsnap((float)actg);
      }
    }
  }
}

extern "C" void kernel_launch(void* const* d_in, const int* in_sizes, int n_in,
                              void* d_out, int out_size, void* d_ws, size_t ws_size,
                              hipStream_t stream) {
  (void)in_sizes; (void)n_in; (void)out_size; (void)d_ws; (void)ws_size;
  hipFuncSetAttribute((const void*)policy_kernel,
                      hipFuncAttributeMaxDynamicSharedMemorySize,
                      (int)sizeof(SmemD));
  policy_kernel<<<BATCH / EPB, 1024, sizeof(SmemD), stream>>>(
      (const float*)d_in[0], (const float*)d_in[1], (const float*)d_in[2],
      (const float*)d_in[3], (const float*)d_in[4], (const float*)d_in[5],
      (const float*)d_in[6], (float*)d_out);
}